// Round 3
// baseline (682.163 us; speedup 1.0000x reference)
//
#include <hip/hip_runtime.h>
#include <math.h>

#define BB 32
#define NN 1024
#define BN (BB*NN)
#define KS 12
#define KCH 256

__device__ __forceinline__ float sigmoidf(float v) { return 1.0f / (1.0f + expf(-v)); }
__device__ __forceinline__ unsigned f2bf(float f) {           // round-to-nearest-even bf16 bits
  unsigned u = __float_as_uint(f);
  return (u + 0x7fffu + ((u >> 16) & 1u)) >> 16;
}

// ---------------- embedding: emb[row][256] ----------------
__global__ void k_emb(const int* __restrict__ xint, const float* __restrict__ xyz,
                      const float* __restrict__ am, const float* __restrict__ el,
                      const float* __restrict__ po, const float* __restrict__ xw,
                      const float* __restrict__ xb, float* __restrict__ emb) {
  int row = blockIdx.x;
  int d = threadIdx.x;
  int i0 = xint[row*3+0], i1 = xint[row*3+1], i2 = xint[row*3+2];
  float v;
  if (d < 28)        v = am[i0*28 + d];
  else if (d < 56)   v = el[i1*28 + (d-28)];
  else if (d < 84)   v = po[i2*28 + (d-56)];
  else {
    int o = d - 84;
    float x0 = xyz[row*3+0], x1 = xyz[row*3+1], x2 = xyz[row*3+2];
    v = fmaxf(xw[o*3+0]*x0 + xw[o*3+1]*x1 + xw[o*3+2]*x2 + xb[o], 0.0f);
  }
  emb[(size_t)row*256 + d] = v;
}

// ---------------- transpose+quantize weights: wt2[k2][j] = pack(bf16 w[2k2][j], bf16 w[2k2+1][j]) ----------------
__global__ __launch_bounds__(256) void k_wt(const float* __restrict__ w_ih,
        const float* __restrict__ w_hh, unsigned* __restrict__ wt2) {
  __shared__ float t[32][33];
  int jt = blockIdx.x * 32, kt = blockIdx.y * 32;
  int tx = threadIdx.x & 31, ty = threadIdx.x >> 5;   // ty 0..7
#pragma unroll
  for (int i = 0; i < 4; i++) {
    int j = jt + ty + i*8;
    int k = kt + tx;
    float v = (k < 2048) ? w_ih[(size_t)j*2048 + k] : w_hh[(size_t)j*1024 + (k - 2048)];
    t[ty + i*8][tx] = v;                              // t[j_local][k_local]
  }
  __syncthreads();
#pragma unroll
  for (int i = 0; i < 2; i++) {
    int kl2 = ty + i*8;                               // 0..15
    float lo = t[tx][kl2*2], hi = t[tx][kl2*2+1];
    unsigned u = (f2bf(hi) << 16) | f2bf(lo);
    wt2[(size_t)((kt >> 1) + kl2)*4096 + jt + tx] = u;
  }
}

// ---------------- Wc partials: wcp[och][k][d] ----------------
__global__ void k_wc1(const float* __restrict__ up_w, const float* __restrict__ att1w,
                      float* __restrict__ wcp) {
  int k = blockIdx.x;       // 128
  int och = blockIdx.y;     // 8
  int d = threadIdx.x;      // 256
  __shared__ float s[128];
  int o0 = och*128;
  if (d < 128) s[d] = att1w[(size_t)k*2048 + 1024 + o0 + d];
  __syncthreads();
  float acc = 0.0f;
#pragma unroll 8
  for (int oi = 0; oi < 128; oi++) acc += up_w[(size_t)(o0+oi)*256 + d] * s[oi];
  wcp[((size_t)och*128 + k)*256 + d] = acc;
}

__global__ void k_wc2(const float* __restrict__ wcp, float* __restrict__ wc) {
  int k = blockIdx.x, d = threadIdx.x;
  float s = 0.0f;
#pragma unroll
  for (int p = 0; p < 8; p++) s += wcp[((size_t)p*128 + k)*256 + d];
  wc[k*256 + d] = s;
}

// ---------------- bc[k] = sum_o up_b[o] * att1_w[k][1024+o] ----------------
__global__ void k_bc(const float* __restrict__ up_b, const float* __restrict__ att1w,
                     float* __restrict__ bc) {
  int k = threadIdx.x;  // 128
  float acc = 0.0f;
  for (int o = 0; o < 1024; o += 4) {
    const float4 a4 = *(const float4*)(att1w + (size_t)k*2048 + 1024 + o);
    acc += up_b[o]*a4.x + up_b[o+1]*a4.y + up_b[o+2]*a4.z + up_b[o+3]*a4.w;
  }
  bc[k] = acc;
}

// ---------------- fp32 GEMM: C[M,Nc] = A[M,K] * W[n][k]^T + bias ----------------
__global__ __launch_bounds__(256) void k_gemm(const float* __restrict__ A, int K,
        const float* __restrict__ W, int ldw, int woff,
        const float* __restrict__ bias, float* __restrict__ C, int Nc) {
  __shared__ float As[16][128];
  __shared__ float Bs[16][128];
  const int m0 = blockIdx.x * 128;
  const int n0 = blockIdx.y * 128;
  const int tid = threadIdx.x;
  const int tx = tid & 15, ty = tid >> 4;
  float acc[8][8];
#pragma unroll
  for (int i = 0; i < 8; i++)
#pragma unroll
    for (int j = 0; j < 8; j++) acc[i][j] = 0.0f;

  for (int kt = 0; kt < K; kt += 16) {
#pragma unroll
    for (int i = 0; i < 2; i++) {
      int s = tid + i*256;
      int r = s >> 2;
      int kq = (s & 3) * 4;
      float4 a4 = *(const float4*)(A + (size_t)(m0 + r)*K + kt + kq);
      As[kq+0][r] = a4.x; As[kq+1][r] = a4.y; As[kq+2][r] = a4.z; As[kq+3][r] = a4.w;
      float4 b4 = *(const float4*)(W + (size_t)(n0 + r)*ldw + woff + kt + kq);
      Bs[kq+0][r] = b4.x; Bs[kq+1][r] = b4.y; Bs[kq+2][r] = b4.z; Bs[kq+3][r] = b4.w;
    }
    __syncthreads();
#pragma unroll
    for (int kk = 0; kk < 16; kk++) {
      float4 a0 = *(const float4*)&As[kk][ty*4];
      float4 a1 = *(const float4*)&As[kk][64 + ty*4];
      float4 b0 = *(const float4*)&Bs[kk][tx*4];
      float4 b1 = *(const float4*)&Bs[kk][64 + tx*4];
      float av[8] = {a0.x,a0.y,a0.z,a0.w,a1.x,a1.y,a1.z,a1.w};
      float bv[8] = {b0.x,b0.y,b0.z,b0.w,b1.x,b1.y,b1.z,b1.w};
#pragma unroll
      for (int i = 0; i < 8; i++)
#pragma unroll
        for (int j = 0; j < 8; j++) acc[i][j] += av[i]*bv[j];
    }
    __syncthreads();
  }
#pragma unroll
  for (int rh = 0; rh < 2; rh++)
#pragma unroll
    for (int i = 0; i < 4; i++) {
      int row = m0 + rh*64 + ty*4 + i;
#pragma unroll
      for (int ch = 0; ch < 2; ch++) {
        int col = n0 + ch*64 + tx*4;
        float4 o;
        o.x = acc[rh*4+i][ch*4+0];
        o.y = acc[rh*4+i][ch*4+1];
        o.z = acc[rh*4+i][ch*4+2];
        o.w = acc[rh*4+i][ch*4+3];
        if (bias) { o.x += bias[col]; o.y += bias[col+1]; o.z += bias[col+2]; o.w += bias[col+3]; }
        *(float4*)(C + (size_t)row*Nc + col) = o;
      }
    }
}

// ---------------- zero h,c ----------------
__global__ void k_zero(float* __restrict__ h, float* __restrict__ c) {
  int i = blockIdx.x * 256 + threadIdx.x;
  h[i] = 0.0f; c[i] = 0.0f;
}

// ---------------- gates partials over bf16-packed transposed weights ----------------
// grid (32 jb, 12 ks); block 256; each block: 128 j x 32 b for one 256-k slice
__global__ __launch_bounds__(256) void k_gates(const float* __restrict__ P, const float* __restrict__ h,
        const unsigned* __restrict__ wt2, float* __restrict__ gp) {
  __shared__ float Xs[32][KCH];     // 32 KB
  int jb = blockIdx.x;              // 0..31
  int ks = blockIdx.y;              // 0..11
  int tid = threadIdx.x;
  int kglob = ks * KCH;
  const float* src; int soff;
  if (ks < 4)      { src = P; soff = kglob; }
  else if (ks < 8) { src = h; soff = kglob - 1024; }
  else             { src = h; soff = kglob - 2048; }
#pragma unroll
  for (int i = 0; i < 8; i++) {
    int s = tid + i*256;            // float4 idx 0..2047
    int b = s >> 6, k4 = s & 63;
    *(float4*)&Xs[b][k4*4] = *(const float4*)(src + b*1024 + soff + k4*4);
  }
  __syncthreads();

  int jg = tid & 31, bg = tid >> 5;        // 32 j-groups x 8 b-groups
  int j0 = jb*128 + jg*4;
  int b0 = bg*4;
  const unsigned* wr = wt2 + (size_t)(kglob >> 1)*4096 + j0;
  float acc[4][4];
#pragma unroll
  for (int i = 0; i < 4; i++)
#pragma unroll
    for (int j = 0; j < 4; j++) acc[i][j] = 0.0f;

  for (int k2 = 0; k2 < KCH/2; k2++) {
    uint4 u4 = *(const uint4*)(wr + (size_t)k2*4096);
    float wlo[4], whi[4];
    wlo[0] = __uint_as_float(u4.x << 16); whi[0] = __uint_as_float(u4.x & 0xffff0000u);
    wlo[1] = __uint_as_float(u4.y << 16); whi[1] = __uint_as_float(u4.y & 0xffff0000u);
    wlo[2] = __uint_as_float(u4.z << 16); whi[2] = __uint_as_float(u4.z & 0xffff0000u);
    wlo[3] = __uint_as_float(u4.w << 16); whi[3] = __uint_as_float(u4.w & 0xffff0000u);
    int k = k2*2;
#pragma unroll
    for (int bi = 0; bi < 4; bi++) {
      float x0 = Xs[b0+bi][k], x1 = Xs[b0+bi][k+1];
#pragma unroll
      for (int ji = 0; ji < 4; ji++) acc[ji][bi] += wlo[ji]*x0 + whi[ji]*x1;
    }
  }
#pragma unroll
  for (int bi = 0; bi < 4; bi++) {
    float4 v = make_float4(acc[0][bi], acc[1][bi], acc[2][bi], acc[3][bi]);
    *(float4*)(gp + ((size_t)ks*32 + b0 + bi)*4096 + j0) = v;
  }
}

// ---------------- reduce gates + LSTM cell + ra ----------------
__global__ __launch_bounds__(256) void k_lstm_ra(const float* __restrict__ gp,
        const float* __restrict__ b_ih, const float* __restrict__ b_hh,
        float* __restrict__ c, float* __restrict__ h,
        const float* __restrict__ att1w, float* __restrict__ ra) {
  int b = blockIdx.x;   // 32
  int t = threadIdx.x;  // 256
  __shared__ float G[4096];
  __shared__ float hs[1024];
#pragma unroll
  for (int i = 0; i < 16; i++) {
    int j = t + i*256;
    float s = b_ih[j] + b_hh[j];
#pragma unroll
    for (int ks = 0; ks < KS; ks++) s += gp[((size_t)ks*32 + b)*4096 + j];
    G[j] = s;
  }
  __syncthreads();
#pragma unroll
  for (int i = 0; i < 4; i++) {
    int d = t + i*256;
    float ig = G[d], fg = G[1024+d], gg = G[2048+d], og = G[3072+d];
    float cn = sigmoidf(fg)*c[b*1024+d] + sigmoidf(ig)*tanhf(gg);
    c[b*1024+d] = cn;
    float hn = sigmoidf(og)*tanhf(cn);
    h[b*1024+d] = hn;
    hs[d] = hn;
  }
  __syncthreads();
  // ra[b][k]: 16 lanes per k, coalesced
  int kg = t >> 4, l16 = t & 15;
  for (int pass = 0; pass < 8; pass++) {
    int k = pass*16 + kg;
    const float* wr = att1w + (size_t)k*2048;
    float acc = 0.0f;
#pragma unroll
    for (int i = 0; i < 16; i++) {
      int d = i*64 + l16*4;
      float4 w4 = *(const float4*)(wr + d);
      acc += w4.x*hs[d] + w4.y*hs[d+1] + w4.z*hs[d+2] + w4.w*hs[d+3];
    }
#pragma unroll
    for (int m = 8; m >= 1; m >>= 1) acc += __shfl_xor(acc, m, 16);
    if (l16 == 0) ra[b*128 + k] = acc;
  }
}

// ---------------- logits + softmax -> normalized weights wn[b][n] ----------------
__global__ __launch_bounds__(256) void k_att_w(const float* __restrict__ xa,
        const float* __restrict__ ra, const float* __restrict__ att1b,
        const float* __restrict__ att2w, const float* __restrict__ att2b,
        float* __restrict__ wn) {
  int b = blockIdx.x;   // 32
  int t = threadIdx.x;  // 256
  __shared__ float rb[128], w2[128];
  __shared__ float lgs[1024];
  __shared__ float red[256];
  if (t < 128) { rb[t] = ra[b*128 + t] + att1b[t]; w2[t] = att2w[t]; }
  __syncthreads();
  int ng = t >> 4, l16 = t & 15;
  float a2b = att2b[0];
  for (int pass = 0; pass < 64; pass++) {
    int n = pass*16 + ng;
    const float* xr = xa + ((size_t)b*1024 + n)*128;
    float acc = 0.0f;
#pragma unroll
    for (int i = 0; i < 2; i++) {
      int kk = (l16 + i*16)*4;
      float4 v = *(const float4*)(xr + kk);
      acc += fmaxf(v.x + rb[kk+0], 0.0f)*w2[kk+0]
           + fmaxf(v.y + rb[kk+1], 0.0f)*w2[kk+1]
           + fmaxf(v.z + rb[kk+2], 0.0f)*w2[kk+2]
           + fmaxf(v.w + rb[kk+3], 0.0f)*w2[kk+3];
    }
#pragma unroll
    for (int m = 8; m >= 1; m >>= 1) acc += __shfl_xor(acc, m, 16);
    if (l16 == 0) lgs[n] = acc + a2b;
  }
  __syncthreads();
  float mx = -1e30f;
#pragma unroll
  for (int i = 0; i < 4; i++) mx = fmaxf(mx, lgs[t + i*256]);
  red[t] = mx; __syncthreads();
  for (int s = 128; s > 0; s >>= 1) { if (t < s) red[t] = fmaxf(red[t], red[t+s]); __syncthreads(); }
  float m = red[0]; __syncthreads();
  float sum = 0.0f;
#pragma unroll
  for (int i = 0; i < 4; i++) sum += expf(lgs[t + i*256] - m);
  red[t] = sum; __syncthreads();
  for (int s = 128; s > 0; s >>= 1) { if (t < s) red[t] += red[t+s]; __syncthreads(); }
  float inv = 1.0f / red[0];
#pragma unroll
  for (int i = 0; i < 4; i++) {
    int n = t + i*256;
    wn[b*1024 + n] = expf(lgs[n] - m) * inv;
  }
}

// ---------------- pooled emb partials: pp[nch][b][d]; wn==nullptr -> uniform ----------------
__global__ void k_poolemb(const float* __restrict__ emb, const float* __restrict__ wn,
                          float* __restrict__ pp) {
  int b = blockIdx.x >> 3, nch = blockIdx.x & 7;
  int t = threadIdx.x;             // 256 (=d)
  int n0 = nch*128;
  __shared__ float ws[128];
  if (t < 128) ws[t] = wn ? wn[b*1024 + n0 + t] : 1.0f;
  __syncthreads();
  float acc = 0.0f;
  const float* eb = emb + (size_t)(b*1024 + n0)*256 + t;
#pragma unroll 4
  for (int n = 0; n < 128; n++) acc += ws[n] * eb[(size_t)n*256];
  pp[(size_t)(nch*32 + b)*256 + t] = acc;
}

// ---------------- fused: pe = scale * sum_p pp ; P[b][o] = pe[b].up_w[o] + up_b[o] ----------------
__global__ __launch_bounds__(256) void k_pool_pgemm(const float* __restrict__ pp,
        const float* __restrict__ up_w, const float* __restrict__ up_b,
        float* __restrict__ Pout, float scale) {
  int o0 = blockIdx.x * 8;           // 128 blocks
  int t = threadIdx.x;
  __shared__ float wsm[8][256];
  __shared__ float pes[32][257];
#pragma unroll
  for (int i = 0; i < 2; i++) {
    int idx = t + i*256;
    int row = idx >> 6, c4 = idx & 63;
    *(float4*)&wsm[row][c4*4] = *(const float4*)(up_w + (size_t)(o0 + row)*256 + c4*4);
  }
#pragma unroll
  for (int i = 0; i < 8; i++) {
    int idx = t + i*256;             // float4 idx 0..2047 over 32x256
    int bq = idx >> 6, c4 = idx & 63;
    float4 s = make_float4(0.f, 0.f, 0.f, 0.f);
#pragma unroll
    for (int p = 0; p < 8; p++) {
      float4 v = *(const float4*)(pp + (size_t)(p*32 + bq)*256 + c4*4);
      s.x += v.x; s.y += v.y; s.z += v.z; s.w += v.w;
    }
    pes[bq][c4*4+0] = s.x*scale; pes[bq][c4*4+1] = s.y*scale;
    pes[bq][c4*4+2] = s.z*scale; pes[bq][c4*4+3] = s.w*scale;
  }
  __syncthreads();
  int b = t & 31, ol = t >> 5;
  float acc = up_b[o0 + ol];
  for (int d = 0; d < 256; d += 4) {
    float4 w4 = *(const float4*)&wsm[ol][d];
    acc += w4.x*pes[b][d] + w4.y*pes[b][d+1] + w4.z*pes[b][d+2] + w4.w*pes[b][d+3];
  }
  Pout[b*1024 + o0 + ol] = acc;
}

// ---------------- final energy ----------------
__global__ void k_out(const float* __restrict__ c, const float* __restrict__ ew,
                      const float* __restrict__ eb, float* __restrict__ out) {
  int b = blockIdx.x, t = threadIdx.x;   // 32 x 64
  float acc = 0.0f;
  for (int d = t; d < 1024; d += 64) acc += c[b*1024 + d] * ew[d];
  for (int off = 32; off > 0; off >>= 1) acc += __shfl_down(acc, off, 64);
  if (t == 0) out[b] = acc + eb[0];
}

extern "C" void kernel_launch(void* const* d_in, const int* in_sizes, int n_in,
                              void* d_out, int out_size, void* d_ws, size_t ws_size,
                              hipStream_t stream) {
  const int*   x_int  = (const int*)d_in[0];
  const float* x_xyz  = (const float*)d_in[1];
  const float* am     = (const float*)d_in[2];
  const float* el     = (const float*)d_in[3];
  const float* po     = (const float*)d_in[4];
  const float* xyz_w  = (const float*)d_in[5];
  const float* xyz_b  = (const float*)d_in[6];
  const float* up_w   = (const float*)d_in[7];
  const float* up_b   = (const float*)d_in[8];
  const float* w_ih   = (const float*)d_in[9];
  const float* w_hh   = (const float*)d_in[10];
  const float* b_ih   = (const float*)d_in[11];
  const float* b_hh   = (const float*)d_in[12];
  const float* att1_w = (const float*)d_in[13];
  const float* att1_b = (const float*)d_in[14];
  const float* att2_w = (const float*)d_in[15];
  const float* att2_b = (const float*)d_in[16];
  const float* en_w   = (const float*)d_in[17];
  const float* en_b   = (const float*)d_in[18];
  float* out = (float*)d_out;

  char* ws = (char*)d_ws;
  size_t off = 0;
  auto alloc = [&](size_t bytes) { void* p = ws + off; off += (bytes + 255) & ~(size_t)255; return p; };
  float*    emb = (float*)alloc((size_t)BN*256*4);       // 33.6 MB
  unsigned* wt2 = (unsigned*)alloc((size_t)1536*4096*4); // 25.2 MB
  float*    xa  = (float*)alloc((size_t)BN*128*4);       // 16.8 MB
  float*    wcp = (float*)alloc((size_t)8*128*256*4);    // 1 MB
  float*    wc  = (float*)alloc((size_t)128*256*4);
  float*    bc  = (float*)alloc((size_t)128*4);
  float*    gp  = (float*)alloc((size_t)KS*32*4096*4);   // 6.3 MB
  float*    pp  = (float*)alloc((size_t)8*32*256*4);     // 256 KB
  float*    P   = (float*)alloc((size_t)32*1024*4);
  float*    h   = (float*)alloc((size_t)32*1024*4);
  float*    c   = (float*)alloc((size_t)32*1024*4);
  float*    ra  = (float*)alloc((size_t)32*128*4);
  float*    wn  = (float*)alloc((size_t)32*1024*4);
  (void)ws_size; (void)in_sizes; (void)n_in; (void)out_size;

  k_zero<<<128, 256, 0, stream>>>(h, c);
  k_emb<<<BN, 256, 0, stream>>>(x_int, x_xyz, am, el, po, xyz_w, xyz_b, emb);
  k_wt<<<dim3(128, 96), 256, 0, stream>>>(w_ih, w_hh, wt2);
  k_wc1<<<dim3(128, 8), 256, 0, stream>>>(up_w, att1_w, wcp);
  k_wc2<<<128, 256, 0, stream>>>(wcp, wc);
  k_bc<<<1, 128, 0, stream>>>(up_b, att1_w, bc);
  // xa = emb @ wc^T + bc   (M=32768, K=256, N=128)
  k_gemm<<<dim3(BN/128, 1), 256, 0, stream>>>(emb, 256, wc, 256, 0, bc, xa, 128);
  // P0 = mean path
  k_poolemb<<<256, 256, 0, stream>>>(emb, nullptr, pp);
  k_pool_pgemm<<<128, 256, 0, stream>>>(pp, up_w, up_b, P, 1.0f/1024.0f);

  for (int step = 0; step < 6; step++) {
    k_gates<<<dim3(32, KS), 256, 0, stream>>>(P, h, wt2, gp);
    k_lstm_ra<<<32, 256, 0, stream>>>(gp, b_ih, b_hh, c, h, att1_w, ra);
    if (step < 5) {  // last step's attention output is unused
      k_att_w<<<32, 256, 0, stream>>>(xa, ra, att1_b, att2_w, att2_b, wn);
      k_poolemb<<<256, 256, 0, stream>>>(emb, wn, pp);
      k_pool_pgemm<<<128, 256, 0, stream>>>(pp, up_w, up_b, P, 1.0f);
    }
  }
  k_out<<<32, 64, 0, stream>>>(c, en_w, en_b, out);
}

// Round 4
// 411.621 us; speedup vs baseline: 1.6573x; 1.6573x over previous
//
#include <hip/hip_runtime.h>
#include <math.h>

#define BB 32
#define NN 1024
#define BN (BB*NN)
#define KS 24
#define KCH 128

__device__ __forceinline__ float sigmoidf(float v) { return 1.0f / (1.0f + expf(-v)); }
__device__ __forceinline__ unsigned f2bf(float f) {           // round-to-nearest-even bf16 bits
  unsigned u = __float_as_uint(f);
  return (u + 0x7fffu + ((u >> 16) & 1u)) >> 16;
}

// ---------------- embedding: emb[row][256] ----------------
__global__ void k_emb(const int* __restrict__ xint, const float* __restrict__ xyz,
                      const float* __restrict__ am, const float* __restrict__ el,
                      const float* __restrict__ po, const float* __restrict__ xw,
                      const float* __restrict__ xb, float* __restrict__ emb) {
  int row = blockIdx.x;
  int d = threadIdx.x;
  int i0 = xint[row*3+0], i1 = xint[row*3+1], i2 = xint[row*3+2];
  float v;
  if (d < 28)        v = am[i0*28 + d];
  else if (d < 56)   v = el[i1*28 + (d-28)];
  else if (d < 84)   v = po[i2*28 + (d-56)];
  else {
    int o = d - 84;
    float x0 = xyz[row*3+0], x1 = xyz[row*3+1], x2 = xyz[row*3+2];
    v = fmaxf(xw[o*3+0]*x0 + xw[o*3+1]*x1 + xw[o*3+2]*x2 + xb[o], 0.0f);
  }
  emb[(size_t)row*256 + d] = v;
}

// ---------------- transpose+quantize weights: wt2[k2][j] = pack(bf16 w[2k2][j], bf16 w[2k2+1][j]) ----------------
__global__ __launch_bounds__(256) void k_wt(const float* __restrict__ w_ih,
        const float* __restrict__ w_hh, unsigned* __restrict__ wt2) {
  __shared__ float t[32][33];
  int jt = blockIdx.x * 32, kt = blockIdx.y * 32;
  int tx = threadIdx.x & 31, ty = threadIdx.x >> 5;   // ty 0..7
#pragma unroll
  for (int i = 0; i < 4; i++) {
    int j = jt + ty + i*8;
    int k = kt + tx;
    float v = (k < 2048) ? w_ih[(size_t)j*2048 + k] : w_hh[(size_t)j*1024 + (k - 2048)];
    t[ty + i*8][tx] = v;                              // t[j_local][k_local]
  }
  __syncthreads();
#pragma unroll
  for (int i = 0; i < 2; i++) {
    int kl2 = ty + i*8;                               // 0..15
    float lo = t[tx][kl2*2], hi = t[tx][kl2*2+1];
    unsigned u = (f2bf(hi) << 16) | f2bf(lo);
    wt2[(size_t)((kt >> 1) + kl2)*4096 + jt + tx] = u;
  }
}

// ---------------- Wc partials: wcp[och][k][d] ----------------
__global__ void k_wc1(const float* __restrict__ up_w, const float* __restrict__ att1w,
                      float* __restrict__ wcp) {
  int k = blockIdx.x;       // 128
  int och = blockIdx.y;     // 8
  int d = threadIdx.x;      // 256
  __shared__ float s[128];
  int o0 = och*128;
  if (d < 128) s[d] = att1w[(size_t)k*2048 + 1024 + o0 + d];
  __syncthreads();
  float acc = 0.0f;
#pragma unroll 8
  for (int oi = 0; oi < 128; oi++) acc += up_w[(size_t)(o0+oi)*256 + d] * s[oi];
  wcp[((size_t)och*128 + k)*256 + d] = acc;
}

__global__ void k_wc2(const float* __restrict__ wcp, float* __restrict__ wc) {
  int k = blockIdx.x, d = threadIdx.x;
  float s = 0.0f;
#pragma unroll
  for (int p = 0; p < 8; p++) s += wcp[((size_t)p*128 + k)*256 + d];
  wc[k*256 + d] = s;
}

// ---------------- bc[k] = sum_o up_b[o] * att1_w[k][1024+o] ----------------
__global__ void k_bc(const float* __restrict__ up_b, const float* __restrict__ att1w,
                     float* __restrict__ bc) {
  int k = blockIdx.x;   // 128 blocks x 64 threads
  int t = threadIdx.x;
  float acc = 0.0f;
#pragma unroll
  for (int i = 0; i < 4; i++) {
    int o = i*256 + t*4;
    float4 a4 = *(const float4*)(att1w + (size_t)k*2048 + 1024 + o);
    float4 b4 = *(const float4*)(up_b + o);
    acc += a4.x*b4.x + a4.y*b4.y + a4.z*b4.z + a4.w*b4.w;
  }
#pragma unroll
  for (int m = 32; m >= 1; m >>= 1) acc += __shfl_xor(acc, m, 64);
  if (t == 0) bc[k] = acc;
}

// ---------------- fp32 GEMM 64x128 tiles: C[M,Nc] = A[M,K]*W[n][k]^T + bias ----------------
__global__ __launch_bounds__(256) void k_gemm(const float* __restrict__ A, int K,
        const float* __restrict__ W, int ldw, int woff,
        const float* __restrict__ bias, float* __restrict__ C, int Nc) {
  __shared__ float As[16][68];
  __shared__ float Bs[16][132];
  const int m0 = blockIdx.x * 64;
  const int n0 = blockIdx.y * 128;
  const int tid = threadIdx.x;
  const int tx = tid & 15, ty = tid >> 4;
  float acc[4][8];
#pragma unroll
  for (int i = 0; i < 4; i++)
#pragma unroll
    for (int j = 0; j < 8; j++) acc[i][j] = 0.0f;

  for (int kt = 0; kt < K; kt += 16) {
    {
      int r = tid >> 2;               // 0..63
      int kq = (tid & 3) * 4;
      float4 a4 = *(const float4*)(A + (size_t)(m0 + r)*K + kt + kq);
      As[kq+0][r] = a4.x; As[kq+1][r] = a4.y; As[kq+2][r] = a4.z; As[kq+3][r] = a4.w;
    }
#pragma unroll
    for (int i = 0; i < 2; i++) {
      int s = tid + i*256;            // 0..511
      int r = s >> 2;                 // 0..127
      int kq = (s & 3) * 4;
      float4 b4 = *(const float4*)(W + (size_t)(n0 + r)*ldw + woff + kt + kq);
      Bs[kq+0][r] = b4.x; Bs[kq+1][r] = b4.y; Bs[kq+2][r] = b4.z; Bs[kq+3][r] = b4.w;
    }
    __syncthreads();
#pragma unroll
    for (int kk = 0; kk < 16; kk++) {
      float4 a0 = *(const float4*)&As[kk][ty*4];
      float4 b0 = *(const float4*)&Bs[kk][tx*4];
      float4 b1 = *(const float4*)&Bs[kk][64 + tx*4];
      float av[4] = {a0.x,a0.y,a0.z,a0.w};
      float bv[8] = {b0.x,b0.y,b0.z,b0.w,b1.x,b1.y,b1.z,b1.w};
#pragma unroll
      for (int i = 0; i < 4; i++)
#pragma unroll
        for (int j = 0; j < 8; j++) acc[i][j] += av[i]*bv[j];
    }
    __syncthreads();
  }
#pragma unroll
  for (int i = 0; i < 4; i++) {
    int row = m0 + ty*4 + i;
#pragma unroll
    for (int ch = 0; ch < 2; ch++) {
      int col = n0 + ch*64 + tx*4;
      float4 o;
      o.x = acc[i][ch*4+0];
      o.y = acc[i][ch*4+1];
      o.z = acc[i][ch*4+2];
      o.w = acc[i][ch*4+3];
      if (bias) { o.x += bias[col]; o.y += bias[col+1]; o.z += bias[col+2]; o.w += bias[col+3]; }
      *(float4*)(C + (size_t)row*Nc + col) = o;
    }
  }
}

// ---------------- zero h,c ----------------
__global__ void k_zero(float* __restrict__ h, float* __restrict__ c) {
  int i = blockIdx.x * 256 + threadIdx.x;
  h[i] = 0.0f; c[i] = 0.0f;
}

// ---------------- gates partials over bf16-packed transposed weights ----------------
// grid (32 jb, 24 ks); block 256; each block: 128 j x 32 b for one 128-k slice
__global__ __launch_bounds__(256) void k_gates(const float* __restrict__ P, const float* __restrict__ h,
        const unsigned* __restrict__ wt2, float* __restrict__ gp) {
  __shared__ float Xs[32][KCH];     // 16 KB
  int jb = blockIdx.x;              // 0..31
  int ks = blockIdx.y;              // 0..23
  int tid = threadIdx.x;
  int kglob = ks * KCH;
  const float* src; int soff;
  if (ks < 8)       { src = P; soff = kglob; }
  else if (ks < 16) { src = h; soff = kglob - 1024; }
  else              { src = h; soff = kglob - 2048; }
#pragma unroll
  for (int i = 0; i < 4; i++) {
    int s = tid + i*256;            // float4 idx 0..1023
    int b = s >> 5, k4 = s & 31;
    *(float4*)&Xs[b][k4*4] = *(const float4*)(src + b*1024 + soff + k4*4);
  }
  __syncthreads();

  int jg = tid & 31, bg = tid >> 5;        // 32 j-groups x 8 b-groups
  int j0 = jb*128 + jg*4;
  int b0 = bg*4;
  const unsigned* wr = wt2 + (size_t)(ks*64)*4096 + j0;
  float acc[4][4];
#pragma unroll
  for (int i = 0; i < 4; i++)
#pragma unroll
    for (int j = 0; j < 4; j++) acc[i][j] = 0.0f;

  for (int k2 = 0; k2 < KCH/2; k2++) {
    uint4 u4 = *(const uint4*)(wr + (size_t)k2*4096);
    float wlo[4], whi[4];
    wlo[0] = __uint_as_float(u4.x << 16); whi[0] = __uint_as_float(u4.x & 0xffff0000u);
    wlo[1] = __uint_as_float(u4.y << 16); whi[1] = __uint_as_float(u4.y & 0xffff0000u);
    wlo[2] = __uint_as_float(u4.z << 16); whi[2] = __uint_as_float(u4.z & 0xffff0000u);
    wlo[3] = __uint_as_float(u4.w << 16); whi[3] = __uint_as_float(u4.w & 0xffff0000u);
    int k = k2*2;
#pragma unroll
    for (int bi = 0; bi < 4; bi++) {
      float x0 = Xs[b0+bi][k], x1 = Xs[b0+bi][k+1];
#pragma unroll
      for (int ji = 0; ji < 4; ji++) acc[ji][bi] += wlo[ji]*x0 + whi[ji]*x1;
    }
  }
#pragma unroll
  for (int bi = 0; bi < 4; bi++) {
    float4 v = make_float4(acc[0][bi], acc[1][bi], acc[2][bi], acc[3][bi]);
    *(float4*)(gp + ((size_t)ks*32 + b0 + bi)*4096 + j0) = v;
  }
}

// ---------------- reduce gates + LSTM cell ----------------
__global__ __launch_bounds__(256) void k_lstm(const float* __restrict__ gp,
        const float* __restrict__ b_ih, const float* __restrict__ b_hh,
        float* __restrict__ c, float* __restrict__ h) {
  int blk = blockIdx.x;            // 128 = b(32) x dch(4)
  int b = blk >> 2, dch = blk & 3;
  int d = dch*256 + threadIdx.x;
  float gi = b_ih[d]        + b_hh[d];
  float gf = b_ih[1024 + d] + b_hh[1024 + d];
  float gg = b_ih[2048 + d] + b_hh[2048 + d];
  float go = b_ih[3072 + d] + b_hh[3072 + d];
#pragma unroll 4
  for (int ks = 0; ks < KS; ks++) {
    const float* base = gp + ((size_t)ks*32 + b)*4096;
    gi += base[d]; gf += base[1024 + d]; gg += base[2048 + d]; go += base[3072 + d];
  }
  float cn = sigmoidf(gf)*c[b*1024 + d] + sigmoidf(gi)*tanhf(gg);
  c[b*1024 + d] = cn;
  h[b*1024 + d] = sigmoidf(go)*tanhf(cn);
}

// ---------------- ra[b][k] = h[b] . att1_w[k][:1024], grid (32 b, 8 kc) ----------------
__global__ __launch_bounds__(256) void k_ra(const float* __restrict__ h,
        const float* __restrict__ att1w, float* __restrict__ ra) {
  int b = blockIdx.x, kc = blockIdx.y;
  int t = threadIdx.x;
  __shared__ float hs[1024];
  *(float4*)&hs[t*4] = *(const float4*)(h + b*1024 + t*4);
  __syncthreads();
  int kg = t >> 4, l16 = t & 15;
  int k = kc*16 + kg;
  const float* wr = att1w + (size_t)k*2048;
  float acc = 0.0f;
#pragma unroll
  for (int i = 0; i < 16; i++) {
    int d = i*64 + l16*4;
    float4 w4 = *(const float4*)(wr + d);
    acc += w4.x*hs[d] + w4.y*hs[d+1] + w4.z*hs[d+2] + w4.w*hs[d+3];
  }
#pragma unroll
  for (int m = 8; m >= 1; m >>= 1) acc += __shfl_xor(acc, m, 16);
  if (l16 == 0) ra[b*128 + k] = acc;
}

// ---------------- logits[b][n], grid (32 b, 8 nc), 2 lanes per n ----------------
__global__ __launch_bounds__(256) void k_logits(const float* __restrict__ xa,
        const float* __restrict__ ra, const float* __restrict__ att1b,
        const float* __restrict__ att2w, const float* __restrict__ att2b,
        float* __restrict__ lg) {
  int b = blockIdx.x, nc = blockIdx.y;
  int t = threadIdx.x;
  __shared__ float rb[128], w2[128];
  if (t < 128) { rb[t] = ra[b*128 + t] + att1b[t]; w2[t] = att2w[t]; }
  __syncthreads();
  int n = nc*128 + (t >> 1);
  int half = (t & 1) * 64;
  const float* xr = xa + ((size_t)b*1024 + n)*128 + half;
  float acc = 0.0f;
#pragma unroll
  for (int i = 0; i < 16; i++) {
    int kk = i*4;
    float4 v = *(const float4*)(xr + kk);
    int kg = half + kk;
    acc += fmaxf(v.x + rb[kg+0], 0.0f)*w2[kg+0]
         + fmaxf(v.y + rb[kg+1], 0.0f)*w2[kg+1]
         + fmaxf(v.z + rb[kg+2], 0.0f)*w2[kg+2]
         + fmaxf(v.w + rb[kg+3], 0.0f)*w2[kg+3];
  }
  acc += __shfl_xor(acc, 1, 64);
  if ((t & 1) == 0) lg[b*1024 + n] = acc + att2b[0];
}

// ---------------- pooled emb partials with in-block softmax; lg==nullptr -> uniform ----------------
__global__ __launch_bounds__(256) void k_poolemb(const float* __restrict__ emb,
        const float* __restrict__ lg, float* __restrict__ pp) {
  int b = blockIdx.x >> 3, nch = blockIdx.x & 7;
  int t = threadIdx.x;             // 256 (=d)
  int n0 = nch*128;
  __shared__ float ws[128];
  __shared__ float red[256];
  if (lg) {
    float mx = -1e30f;
#pragma unroll
    for (int i = 0; i < 4; i++) mx = fmaxf(mx, lg[b*1024 + t + i*256]);
    red[t] = mx; __syncthreads();
    for (int s = 128; s > 0; s >>= 1) { if (t < s) red[t] = fmaxf(red[t], red[t+s]); __syncthreads(); }
    float m = red[0]; __syncthreads();
    float sum = 0.0f;
#pragma unroll
    for (int i = 0; i < 4; i++) sum += expf(lg[b*1024 + t + i*256] - m);
    red[t] = sum; __syncthreads();
    for (int s = 128; s > 0; s >>= 1) { if (t < s) red[t] += red[t+s]; __syncthreads(); }
    float inv = 1.0f / red[0];
    if (t < 128) ws[t] = expf(lg[b*1024 + n0 + t] - m) * inv;
  } else {
    if (t < 128) ws[t] = 1.0f;
  }
  __syncthreads();
  float acc = 0.0f;
  const float* eb = emb + (size_t)(b*1024 + n0)*256 + t;
#pragma unroll 4
  for (int n = 0; n < 128; n++) acc += ws[n] * eb[(size_t)n*256];
  pp[(size_t)(nch*32 + b)*256 + t] = acc;
}

// ---------------- fused: pe = scale * sum_p pp ; P[b][o] = pe[b].up_w[o] + up_b[o] ----------------
__global__ __launch_bounds__(256) void k_pool_pgemm(const float* __restrict__ pp,
        const float* __restrict__ up_w, const float* __restrict__ up_b,
        float* __restrict__ Pout, float scale) {
  int o0 = blockIdx.x * 8;           // 128 blocks
  int t = threadIdx.x;
  __shared__ float wsm[8][256];
  __shared__ float pes[32][257];
#pragma unroll
  for (int i = 0; i < 2; i++) {
    int idx = t + i*256;
    int row = idx >> 6, c4 = idx & 63;
    *(float4*)&wsm[row][c4*4] = *(const float4*)(up_w + (size_t)(o0 + row)*256 + c4*4);
  }
#pragma unroll
  for (int i = 0; i < 8; i++) {
    int idx = t + i*256;             // float4 idx 0..2047 over 32x256
    int bq = idx >> 6, c4 = idx & 63;
    float4 s = make_float4(0.f, 0.f, 0.f, 0.f);
#pragma unroll
    for (int p = 0; p < 8; p++) {
      float4 v = *(const float4*)(pp + (size_t)(p*32 + bq)*256 + c4*4);
      s.x += v.x; s.y += v.y; s.z += v.z; s.w += v.w;
    }
    pes[bq][c4*4+0] = s.x*scale; pes[bq][c4*4+1] = s.y*scale;
    pes[bq][c4*4+2] = s.z*scale; pes[bq][c4*4+3] = s.w*scale;
  }
  __syncthreads();
  int b = t & 31, ol = t >> 5;
  float acc = up_b[o0 + ol];
  for (int d = 0; d < 256; d += 4) {
    float4 w4 = *(const float4*)&wsm[ol][d];
    acc += w4.x*pes[b][d] + w4.y*pes[b][d+1] + w4.z*pes[b][d+2] + w4.w*pes[b][d+3];
  }
  Pout[b*1024 + o0 + ol] = acc;
}

// ---------------- final energy ----------------
__global__ void k_out(const float* __restrict__ c, const float* __restrict__ ew,
                      const float* __restrict__ eb, float* __restrict__ out) {
  int b = blockIdx.x, t = threadIdx.x;   // 32 x 64
  float acc = 0.0f;
  for (int d = t; d < 1024; d += 64) acc += c[b*1024 + d] * ew[d];
  for (int off = 32; off > 0; off >>= 1) acc += __shfl_down(acc, off, 64);
  if (t == 0) out[b] = acc + eb[0];
}

extern "C" void kernel_launch(void* const* d_in, const int* in_sizes, int n_in,
                              void* d_out, int out_size, void* d_ws, size_t ws_size,
                              hipStream_t stream) {
  const int*   x_int  = (const int*)d_in[0];
  const float* x_xyz  = (const float*)d_in[1];
  const float* am     = (const float*)d_in[2];
  const float* el     = (const float*)d_in[3];
  const float* po     = (const float*)d_in[4];
  const float* xyz_w  = (const float*)d_in[5];
  const float* xyz_b  = (const float*)d_in[6];
  const float* up_w   = (const float*)d_in[7];
  const float* up_b   = (const float*)d_in[8];
  const float* w_ih   = (const float*)d_in[9];
  const float* w_hh   = (const float*)d_in[10];
  const float* b_ih   = (const float*)d_in[11];
  const float* b_hh   = (const float*)d_in[12];
  const float* att1_w = (const float*)d_in[13];
  const float* att1_b = (const float*)d_in[14];
  const float* att2_w = (const float*)d_in[15];
  const float* att2_b = (const float*)d_in[16];
  const float* en_w   = (const float*)d_in[17];
  const float* en_b   = (const float*)d_in[18];
  float* out = (float*)d_out;

  char* ws = (char*)d_ws;
  size_t off = 0;
  auto alloc = [&](size_t bytes) { void* p = ws + off; off += (bytes + 255) & ~(size_t)255; return p; };
  float*    emb = (float*)alloc((size_t)BN*256*4);       // 33.6 MB
  unsigned* wt2 = (unsigned*)alloc((size_t)1536*4096*4); // 25.2 MB
  float*    xa  = (float*)alloc((size_t)BN*128*4);       // 16.8 MB
  float*    wcp = (float*)alloc((size_t)8*128*256*4);    // 1 MB
  float*    wc  = (float*)alloc((size_t)128*256*4);
  float*    bc  = (float*)alloc((size_t)128*4);
  float*    gp  = (float*)alloc((size_t)KS*32*4096*4);   // 12.6 MB
  float*    pp  = (float*)alloc((size_t)8*32*256*4);     // 256 KB
  float*    P   = (float*)alloc((size_t)32*1024*4);
  float*    h   = (float*)alloc((size_t)32*1024*4);
  float*    c   = (float*)alloc((size_t)32*1024*4);
  float*    ra  = (float*)alloc((size_t)32*128*4);
  float*    lg  = (float*)alloc((size_t)32*1024*4);
  (void)ws_size; (void)in_sizes; (void)n_in; (void)out_size;

  k_zero<<<128, 256, 0, stream>>>(h, c);
  k_emb<<<BN, 256, 0, stream>>>(x_int, x_xyz, am, el, po, xyz_w, xyz_b, emb);
  k_wt<<<dim3(128, 96), 256, 0, stream>>>(w_ih, w_hh, wt2);
  k_wc1<<<dim3(128, 8), 256, 0, stream>>>(up_w, att1_w, wcp);
  k_wc2<<<128, 256, 0, stream>>>(wcp, wc);
  k_bc<<<128, 64, 0, stream>>>(up_b, att1_w, bc);
  // xa = emb @ wc^T + bc   (M=32768, K=256, N=128)
  k_gemm<<<dim3(BN/64, 1), 256, 0, stream>>>(emb, 256, wc, 256, 0, bc, xa, 128);
  // P0 = mean path
  k_poolemb<<<256, 256, 0, stream>>>(emb, nullptr, pp);
  k_pool_pgemm<<<128, 256, 0, stream>>>(pp, up_w, up_b, P, 1.0f/1024.0f);

  for (int step = 0; step < 6; step++) {
    k_gates<<<dim3(32, KS), 256, 0, stream>>>(P, h, wt2, gp);
    k_lstm<<<128, 256, 0, stream>>>(gp, b_ih, b_hh, c, h);
    if (step < 5) {  // last step's attention output is unused
      k_ra<<<dim3(32, 8), 256, 0, stream>>>(h, att1_w, ra);
      k_logits<<<dim3(32, 8), 256, 0, stream>>>(xa, ra, att1_b, att2_w, att2_b, lg);
      k_poolemb<<<256, 256, 0, stream>>>(emb, lg, pp);
      k_pool_pgemm<<<128, 256, 0, stream>>>(pp, up_w, up_b, P, 1.0f);
    }
  }
  k_out<<<32, 64, 0, stream>>>(c, en_w, en_b, out);
}